// Round 10
// baseline (577.407 us; speedup 1.0000x reference)
//
#include <hip/hip_runtime.h>
#include <hip/hip_cooperative_groups.h>
#include <cstdint>
#include <cstddef>

namespace cg = cooperative_groups;

#define CHUNK 8192
#define SPLITS 8

typedef __attribute__((ext_vector_type(8))) short short8;
typedef __attribute__((ext_vector_type(4))) float f32x4;
typedef __attribute__((ext_vector_type(2))) float f32x2;
typedef __attribute__((ext_vector_type(4))) unsigned int u32x4;

__device__ __forceinline__ float bf2f(unsigned short u) {
  return __uint_as_float(((unsigned)u) << 16);
}
__device__ __forceinline__ unsigned short f2bf(float f) {
  unsigned u = __float_as_uint(f);
  u += 0x7fffu + ((u >> 16) & 1u);   // RNE
  return (unsigned short)(u >> 16);
}
__device__ __forceinline__ f32x2 unpk(unsigned u) {
  f32x2 r;
  r.x = __uint_as_float(u << 16);
  r.y = __uint_as_float(u & 0xffff0000u);
  return r;
}
__device__ __forceinline__ void pkfma(f32x2& a, f32x2 b, f32x2 c) {
  asm("v_pk_fma_f32 %0, %1, %2, %0" : "+v"(a) : "v"(b), "v"(c));
}

// shared-memory overlay for all phases
union SMemX {
  unsigned short ws[128 * 136];                          // 34816 B (gemm)
  struct { unsigned sorted[CHUNK];
           int h[256]; int lps[256]; int base_s[256]; int cur[256]; } sc;  // 36864 B
  struct { int c[256]; int cur[256]; int sb[256];
           unsigned short colL[12288]; } cf;             // 27648 B
  struct { float red[16][136]; } pl;                     // 8704 B
  struct { float gs[128]; float zs[128]; } cl;           // 1024 B
};

// ---------------- gemm tile body: 128-row tiles, 512 threads ----------------
template <bool AF32, bool WF32>
__device__ __forceinline__ void gemm_tile(SMemX& sm, const void* Ap,
                                          const void* Wp,
                                          unsigned short* C, int N, int tile) {
  if (WF32) {
    const float* Wf = (const float*)Wp;
    for (int idx = threadIdx.x; idx < 16384; idx += 512) {
      int k = idx >> 7, n = idx & 127;
      sm.ws[n * 136 + k] = f2bf(Wf[idx]);
    }
  } else {
    const unsigned short* Wt = (const unsigned short*)Wp;
    for (int idx = threadIdx.x; idx < 2048; idx += 512) {
      int n = idx >> 4, c = idx & 15;
      *(uint4*)&sm.ws[n * 136 + c * 8] = ((const uint4*)Wt)[idx];
    }
  }
  __syncthreads();
  const int w = threadIdx.x >> 6;        // 0..7
  const int lane = threadIdx.x & 63;
  const int quad = lane >> 4, l16 = lane & 15;
  const int r = tile * 128 + w * 16 + l16;
  f32x4 acc[8] = {};
  #pragma unroll
  for (int ks = 0; ks < 4; ks++) {
    short8 a = {};
    if (r < N) {
      if (AF32) {
        const float* ar = (const float*)Ap + (size_t)r * 128 + ks * 32 + quad * 8;
        float4 u0 = *(const float4*)ar;
        float4 u1 = *(const float4*)(ar + 4);
        a[0] = (short)f2bf(u0.x); a[1] = (short)f2bf(u0.y);
        a[2] = (short)f2bf(u0.z); a[3] = (short)f2bf(u0.w);
        a[4] = (short)f2bf(u1.x); a[5] = (short)f2bf(u1.y);
        a[6] = (short)f2bf(u1.z); a[7] = (short)f2bf(u1.w);
      } else {
        a = *(const short8*)((const unsigned short*)Ap + (size_t)r * 128 + ks * 32 + quad * 8);
      }
    }
    #pragma unroll
    for (int t = 0; t < 8; t++) {
      short8 bF = *(const short8*)&sm.ws[(t * 16 + l16) * 136 + ks * 32 + quad * 8];
      acc[t] = __builtin_amdgcn_mfma_f32_16x16x32_bf16(a, bF, acc[t], 0, 0, 0);
    }
  }
  __syncthreads();
  unsigned short* Cs = sm.ws;
  {
    int rloc = w * 16 + quad * 4;
    #pragma unroll
    for (int t = 0; t < 8; t++)
      #pragma unroll
      for (int rg = 0; rg < 4; rg++)
        Cs[(rloc + rg) * 132 + t * 16 + l16] = f2bf(acc[t][rg]);
  }
  __syncthreads();
  const int r0 = tile * 128;
  for (int idx = threadIdx.x; idx < 2048; idx += 512) {
    int row = idx >> 4, c = idx & 15;
    int rr = r0 + row;
    if (rr < N) {
      uint2 a = *(uint2*)&Cs[row * 132 + c * 8];
      uint2 b = *(uint2*)&Cs[row * 132 + c * 8 + 4];
      ((uint4*)C)[(size_t)rr * 16 + c] = make_uint4(a.x, a.y, b.x, b.y);
    }
  }
}

// ---------------- scatter block (LDS counting sort), 512 threads ----------------
__device__ __forceinline__ void scatter_block(SMemX& sm, const int* __restrict__ src,
                                              const int* __restrict__ dst, int E,
                                              int* __restrict__ gcur,
                                              unsigned int* __restrict__ tmp,
                                              int cap, int B, int cblk) {
  const int t = threadIdx.x;
  if (t < 256) sm.sc.h[t] = 0;
  __syncthreads();
  int e0 = cblk * CHUNK;
  int e1 = e0 + CHUNK; if (e1 > E) e1 = E;
  int m = e1 - e0;
  for (int i = t; i < m; i += 512) {
    atomicAdd(&sm.sc.h[dst[e0 + i] >> 8], 1);
  }
  __syncthreads();
  int v = (t < 256) ? sm.sc.h[t] : 0;
  if (t < 256) sm.sc.lps[t] = v;
  __syncthreads();
  for (int off = 1; off < 256; off <<= 1) {
    int u = (t >= off && t < 256) ? sm.sc.lps[t - off] : 0;
    __syncthreads();
    if (t < 256) sm.sc.lps[t] += u;
    __syncthreads();
  }
  int incl = (t < 256) ? sm.sc.lps[t] : 0;
  if (t < B && v > 0) sm.sc.base_s[t] = atomicAdd(&gcur[t], v);
  if (t < 256) {
    sm.sc.cur[t] = 0;
    sm.sc.lps[t] = incl - v;
  }
  __syncthreads();
  for (int i = t; i < m; i += 512) {
    int d = dst[e0 + i], s = src[e0 + i];
    int b = d >> 8;
    int r = atomicAdd(&sm.sc.cur[b], 1);
    sm.sc.sorted[sm.sc.lps[b] + r] = ((unsigned)b << 24) | ((unsigned)s << 8) | (unsigned)(d & 255);
  }
  __syncthreads();
  for (int i = t; i < m; i += 512) {
    unsigned u = sm.sc.sorted[i];
    int b = u >> 24;
    int p = sm.sc.base_s[b] + (i - sm.sc.lps[b]);
    if (p < cap) tmp[(size_t)b * cap + p] = u;
  }
  __syncthreads();
}

// ---------------- cntfill block, 512 threads ----------------
__device__ __forceinline__ void cntfill_block(SMemX& sm, const unsigned int* __restrict__ tmp,
                                              const int* __restrict__ gcur,
                                              int N, int cap, int B,
                                              float* __restrict__ dinv,
                                              int* __restrict__ rs,
                                              unsigned short* __restrict__ col, int b) {
  const int t = threadIdx.x;
  int cb = 0;
  if (t < B) { cb = gcur[t]; if (cb > cap) cb = cap; }
  if (t < 256) sm.cf.sb[t] = cb;
  __syncthreads();
  for (int off = 1; off < 256; off <<= 1) {
    int u = (t >= off && t < 256) ? sm.cf.sb[t - off] : 0;
    __syncthreads();
    if (t < 256) sm.cf.sb[t] += u;
    __syncthreads();
  }
  int base_b = (b > 0) ? sm.cf.sb[b - 1] : 0;
  int cnt_b = sm.cf.sb[b] - base_b;
  if (b == 0 && t == 0) rs[N] = sm.cf.sb[B - 1];
  const unsigned* tb = tmp + (size_t)b * cap;
  if (t < 256) sm.cf.c[t] = 0;
  __syncthreads();
  for (int i = t; i < cnt_b; i += 512) atomicAdd(&sm.cf.c[tb[i] & 255u], 1);
  __syncthreads();
  int v = (t < 256) ? sm.cf.c[t] : 0;
  if (t < 256) sm.cf.cur[t] = v;
  __syncthreads();
  for (int off = 1; off < 256; off <<= 1) {
    int u = (t >= off && t < 256) ? sm.cf.cur[t - off] : 0;
    __syncthreads();
    if (t < 256) sm.cf.cur[t] += u;
    __syncthreads();
  }
  int rsv = (t < 256) ? (base_b + sm.cf.cur[t] - v) : 0;
  int node = (b << 8) + t;
  if (t < 256 && node < N) {
    rs[node] = rsv;
    dinv[node] = rsqrtf((float)v + 1.0f);
  }
  __syncthreads();
  if (cnt_b <= 12288) {
    if (t < 256) sm.cf.cur[t] = rsv - base_b;
    __syncthreads();
    for (int i = t; i < cnt_b; i += 512) {
      unsigned u = tb[i];
      int lpos = atomicAdd(&sm.cf.cur[u & 255u], 1);
      sm.cf.colL[lpos] = (unsigned short)((u >> 8) & 0xFFFFu);
    }
    __syncthreads();
    for (int i = t; i < cnt_b; i += 512) col[base_b + i] = sm.cf.colL[i];
  } else {
    if (t < 256) sm.cf.cur[t] = rsv;
    __syncthreads();
    for (int i = t; i < cnt_b; i += 512) {
      unsigned u = tb[i];
      int pos = atomicAdd(&sm.cf.cur[u & 255u], 1);
      col[pos] = (unsigned short)((u >> 8) & 0xFFFFu);
    }
  }
  __syncthreads();
}

// ---------------- shared agg body: 32-edge unclamped fast path + 16-edge tail ----
template <typename CT>
__device__ __forceinline__ void agg_body(f32x2 (&acc2)[4],
                                         const unsigned short* __restrict__ h,
                                         const CT* __restrict__ col,
                                         const float* __restrict__ dinv,
                                         int beg, int end, int g, int l) {
  int base = beg;
  for (; base + 32 <= end; base += 32) {
    int s[8];
    float w[8];
    uint4 H[8];
    #pragma unroll
    for (int k = 0; k < 8; k++) s[k] = (int)col[base + 4 * k + g];
    #pragma unroll
    for (int k = 0; k < 8; k++) w[k] = dinv[s[k]];
    #pragma unroll
    for (int k = 0; k < 8; k++) H[k] = ((const uint4*)(h + (size_t)s[k] * 128))[l];
    #pragma unroll
    for (int k = 0; k < 8; k++) {
      f32x2 wv; wv.x = w[k]; wv.y = w[k];
      pkfma(acc2[0], unpk(H[k].x), wv);
      pkfma(acc2[1], unpk(H[k].y), wv);
      pkfma(acc2[2], unpk(H[k].z), wv);
      pkfma(acc2[3], unpk(H[k].w), wv);
    }
  }
  for (; base < end; base += 16) {
    int e0 = base + g, e1 = base + 4 + g, e2 = base + 8 + g, e3 = base + 12 + g;
    int i0 = (e0 < end) ? e0 : end - 1;
    int i1 = (e1 < end) ? e1 : end - 1;
    int i2 = (e2 < end) ? e2 : end - 1;
    int i3 = (e3 < end) ? e3 : end - 1;
    int s0 = (int)col[i0], s1 = (int)col[i1], s2 = (int)col[i2], s3 = (int)col[i3];
    float w0 = (e0 < end) ? dinv[s0] : 0.f;
    float w1 = (e1 < end) ? dinv[s1] : 0.f;
    float w2 = (e2 < end) ? dinv[s2] : 0.f;
    float w3 = (e3 < end) ? dinv[s3] : 0.f;
    uint4 h0 = ((const uint4*)(h + (size_t)s0 * 128))[l];
    uint4 h1 = ((const uint4*)(h + (size_t)s1 * 128))[l];
    uint4 h2 = ((const uint4*)(h + (size_t)s2 * 128))[l];
    uint4 h3 = ((const uint4*)(h + (size_t)s3 * 128))[l];
    f32x2 w0v; w0v.x = w0; w0v.y = w0;
    f32x2 w1v; w1v.x = w1; w1v.y = w1;
    f32x2 w2v; w2v.x = w2; w2v.y = w2;
    f32x2 w3v; w3v.x = w3; w3v.y = w3;
    pkfma(acc2[0], unpk(h0.x), w0v); pkfma(acc2[0], unpk(h1.x), w1v);
    pkfma(acc2[0], unpk(h2.x), w2v); pkfma(acc2[0], unpk(h3.x), w3v);
    pkfma(acc2[1], unpk(h0.y), w0v); pkfma(acc2[1], unpk(h1.y), w1v);
    pkfma(acc2[1], unpk(h2.y), w2v); pkfma(acc2[1], unpk(h3.y), w3v);
    pkfma(acc2[2], unpk(h0.z), w0v); pkfma(acc2[2], unpk(h1.z), w1v);
    pkfma(acc2[2], unpk(h2.z), w2v); pkfma(acc2[2], unpk(h3.z), w3v);
    pkfma(acc2[3], unpk(h0.w), w0v); pkfma(acc2[3], unpk(h1.w), w1v);
    pkfma(acc2[3], unpk(h2.w), w2v); pkfma(acc2[3], unpk(h3.w), w3v);
  }
  #pragma unroll
  for (int j = 0; j < 4; j++) {
    acc2[j].x += __shfl_xor(acc2[j].x, 16);
    acc2[j].y += __shfl_xor(acc2[j].y, 16);
    acc2[j].x += __shfl_xor(acc2[j].x, 32);
    acc2[j].y += __shfl_xor(acc2[j].y, 32);
  }
}

// per-wave node aggregation, grid-strided (512 thr = 8 waves/block)
template <typename CT>
__device__ __forceinline__ void agg_phase(const unsigned short* __restrict__ h,
                                          const int* __restrict__ rs,
                                          const CT* __restrict__ col,
                                          const float* __restrict__ dinv,
                                          const float* __restrict__ bias,
                                          unsigned short* __restrict__ outp,
                                          int n, int bid, int NB) {
  const int t = threadIdx.x;
  const int w = t >> 6;
  const int lane = t & 63;
  const int g = lane >> 4;
  const int l = lane & 15;
  for (int wid = bid * 8 + w; wid < n; wid += NB * 8) {
    float di = dinv[wid];
    f32x2 acc2[4];
    {
      uint4 sv = ((const uint4*)(h + (size_t)wid * 128))[l];
      float ws = (g == 0) ? di : 0.f;
      f32x2 wv; wv.x = ws; wv.y = ws;
      acc2[0] = unpk(sv.x) * wv;
      acc2[1] = unpk(sv.y) * wv;
      acc2[2] = unpk(sv.z) * wv;
      acc2[3] = unpk(sv.w) * wv;
    }
    agg_body<CT>(acc2, h, col, dinv, rs[wid], rs[wid + 1], g, l);
    if (g == 0) {
      float4 bA = *(const float4*)(bias + l * 8);
      float4 bB = *(const float4*)(bias + l * 8 + 4);
      float r0 = fmaxf(acc2[0].x * di + bA.x, 0.f);
      float r1 = fmaxf(acc2[0].y * di + bA.y, 0.f);
      float r2 = fmaxf(acc2[1].x * di + bA.z, 0.f);
      float r3 = fmaxf(acc2[1].y * di + bA.w, 0.f);
      float r4 = fmaxf(acc2[2].x * di + bB.x, 0.f);
      float r5 = fmaxf(acc2[2].y * di + bB.y, 0.f);
      float r6 = fmaxf(acc2[3].x * di + bB.z, 0.f);
      float r7 = fmaxf(acc2[3].y * di + bB.w, 0.f);
      u32x4 v;
      v.x = (unsigned)f2bf(r0) | ((unsigned)f2bf(r1) << 16);
      v.y = (unsigned)f2bf(r2) | ((unsigned)f2bf(r3) << 16);
      v.z = (unsigned)f2bf(r4) | ((unsigned)f2bf(r5) << 16);
      v.w = (unsigned)f2bf(r6) | ((unsigned)f2bf(r7) << 16);
      __builtin_nontemporal_store(v, (u32x4*)outp + (size_t)wid * 16 + l);
    }
  }
}

// ---------------- pool slice (t<256 active) ----------------
__device__ __forceinline__ void pool_block(SMemX& sm, const unsigned short* __restrict__ h,
                                           const int* __restrict__ bat, int n,
                                           float* __restrict__ gsums, int s) {
  const int t = threadIdx.x;
  const int g = s / SPLITS;
  const int sp = s % SPLITS;
  const int slot = (t >> 4) & 15;
  const int seg = t & 15;
  int lo;
  { int l = 0, r = n; while (l < r) { int m = (l + r) >> 1; if (bat[m] < g) l = m + 1; else r = m; } lo = l; }
  int hi;
  { int l = lo, r = n; while (l < r) { int m = (l + r) >> 1; if (bat[m] < g + 1) l = m + 1; else r = m; } hi = l; }
  int L = hi - lo;
  int chunk = (L + SPLITS - 1) / SPLITS;
  int i0 = lo + sp * chunk;
  int i1 = i0 + chunk; if (i1 > hi) i1 = hi;
  if (i0 >= i1) return;   // uniform per block
  if (t < 256) {
    float a0 = 0.f, a1 = 0.f, a2 = 0.f, a3 = 0.f, a4 = 0.f, a5 = 0.f, a6 = 0.f, a7 = 0.f;
    for (int i = i0 + slot; i < i1; i += 16) {
      uint4 v = ((const uint4*)(h + (size_t)i * 128))[seg];
      a0 += bf2f((unsigned short)v.x);  a1 += bf2f((unsigned short)(v.x >> 16));
      a2 += bf2f((unsigned short)v.y);  a3 += bf2f((unsigned short)(v.y >> 16));
      a4 += bf2f((unsigned short)v.z);  a5 += bf2f((unsigned short)(v.z >> 16));
      a6 += bf2f((unsigned short)v.w);  a7 += bf2f((unsigned short)(v.w >> 16));
    }
    sm.pl.red[slot][seg * 8 + 0] = a0; sm.pl.red[slot][seg * 8 + 1] = a1;
    sm.pl.red[slot][seg * 8 + 2] = a2; sm.pl.red[slot][seg * 8 + 3] = a3;
    sm.pl.red[slot][seg * 8 + 4] = a4; sm.pl.red[slot][seg * 8 + 5] = a5;
    sm.pl.red[slot][seg * 8 + 6] = a6; sm.pl.red[slot][seg * 8 + 7] = a7;
  }
  __syncthreads();
  if (t < 128) {
    float ssum = 0.f;
    #pragma unroll
    for (int k = 0; k < 16; k++) ssum += sm.pl.red[k][t];
    unsafeAtomicAdd(&gsums[g * 128 + t], ssum);
  }
  __syncthreads();
}

// ---------------- classify (t<256 active) ----------------
__device__ __forceinline__ void classify_block(SMemX& sm, const float* __restrict__ gsums,
                                               const int* __restrict__ bat, int n,
                                               const float* __restrict__ Wc1,
                                               const float* __restrict__ bc1,
                                               const float* __restrict__ Wc2,
                                               const float* __restrict__ bc2,
                                               float* __restrict__ out, int nc, int g) {
  const int t = threadIdx.x;
  int lo;
  { int l = 0, r = n; while (l < r) { int m = (l + r) >> 1; if (bat[m] < g) l = m + 1; else r = m; } lo = l; }
  int hi;
  { int l = lo, r = n; while (l < r) { int m = (l + r) >> 1; if (bat[m] < g + 1) l = m + 1; else r = m; } hi = l; }
  if (t < 128) {
    float c = (float)(hi - lo); if (c < 1.f) c = 1.f;
    sm.cl.gs[t] = gsums[g * 128 + t] / c;
  }
  __syncthreads();
  if (t < 128) {
    float a = bc1[t];
    for (int k = 0; k < 128; k++) a += sm.cl.gs[k] * Wc1[k * 128 + t];
    sm.cl.zs[t] = fmaxf(a, 0.f);
  }
  __syncthreads();
  if (t < nc) {
    float o = bc2[t];
    for (int k = 0; k < 128; k++) o += sm.cl.zs[k] * Wc2[k * nc + t];
    out[g * nc + t] = o;
  }
  __syncthreads();
}

// ---------------- the cooperative mega-kernel (small-N path) ----------------
__global__ __launch_bounds__(512) void mega_k(
    const int* __restrict__ src, const int* __restrict__ dst, int E,
    int* __restrict__ gcur, unsigned int* __restrict__ tmp, int cap, int B,
    const float* __restrict__ x, const float* __restrict__ W1,
    const float* __restrict__ W2,
    const float* __restrict__ b1v, const float* __restrict__ b2v,
    const int* __restrict__ bat,
    const float* __restrict__ Wc1, const float* __restrict__ bc1,
    const float* __restrict__ Wc2, const float* __restrict__ bc2,
    float* __restrict__ out, int NC, int G,
    unsigned short* __restrict__ B2, unsigned short* __restrict__ B3,
    float* __restrict__ dinv, int* __restrict__ rs,
    unsigned short* __restrict__ col,
    float* __restrict__ gsums, int N, int nblk, int gblocks) {
  __shared__ SMemX sm;
  cg::grid_group grid = cg::this_grid();
  const int t = threadIdx.x;
  const int bid = blockIdx.x;
  const int NB = gridDim.x;
  // P0: zero gsums + gcur
  for (int i = bid * 512 + t; i < G * 128; i += NB * 512) gsums[i] = 0.f;
  if (bid == 0 && t < 256) gcur[t] = 0;
  grid.sync();
  // P1: scatter (bucketed counting sort)
  for (int c = bid; c < nblk; c += NB) scatter_block(sm, src, dst, E, gcur, tmp, cap, B, c);
  grid.sync();
  // P2: cntfill (bid < B) || gemm1 x*W1 -> B2 (others)
  if (bid < B) {
    cntfill_block(sm, tmp, gcur, N, cap, B, dinv, rs, col, bid);
  } else {
    for (int tile = bid - B; tile < gblocks; tile += NB - B) {
      gemm_tile<true, true>(sm, x, W1, B2, N, tile);
      __syncthreads();
    }
  }
  grid.sync();
  // P3: agg layer 1: B2 -> B3 (+b1, relu)
  agg_phase<unsigned short>(B2, rs, col, dinv, b1v, B3, N, bid, NB);
  grid.sync();
  // P4: gemm2: B3*W2 -> B2
  for (int tile = bid; tile < gblocks; tile += NB) {
    gemm_tile<false, true>(sm, B3, W2, B2, N, tile);
    __syncthreads();
  }
  grid.sync();
  // P5: agg layer 2: B2 -> B3 (+b2, relu)
  agg_phase<unsigned short>(B2, rs, col, dinv, b2v, B3, N, bid, NB);
  grid.sync();
  // P6: mean-pool partial sums
  for (int s = bid; s < G * SPLITS; s += NB) pool_block(sm, B3, bat, N, gsums, s);
  grid.sync();
  // P7: classifier
  for (int g = bid; g < G; g += NB)
    classify_block(sm, gsums, bat, N, Wc1, bc1, Wc2, bc2, out, NC, g);
}

// ================= fallback kernels (round-9 versions, unchanged logic) =================

__global__ void prep_k(const float* __restrict__ W1, const float* __restrict__ W2,
                       unsigned short* __restrict__ W1t, unsigned short* __restrict__ W2t,
                       int* __restrict__ gcur, int B,
                       float* __restrict__ gsums, int GN) {
  int idx = blockIdx.x * 256 + threadIdx.x;
  const float* W = (idx < 16384) ? W1 : W2;
  unsigned short* Wt = (idx < 16384) ? W1t : W2t;
  int i = idx & 16383;
  int k = i >> 7, n = i & 127;
  Wt[n * 128 + k] = f2bf(W[i]);
  if (blockIdx.x == 0 && threadIdx.x < B) gcur[threadIdx.x] = 0;
  if (idx < GN) gsums[idx] = 0.f;
}

__global__ __launch_bounds__(512) void scat_gemm1a_k(const int* __restrict__ src,
                                                     const int* __restrict__ dst, int E,
                                                     int* __restrict__ gcur,
                                                     unsigned int* __restrict__ tmp,
                                                     int cap, int B,
                                                     const float* __restrict__ x,
                                                     const float* __restrict__ W1,
                                                     unsigned short* __restrict__ B2, int N,
                                                     int nblk, int T1,
                                                     const float* __restrict__ W2,
                                                     unsigned short* __restrict__ W2t,
                                                     int P2) {
  __shared__ SMemX sm;
  const int t = threadIdx.x;
  const int bid = blockIdx.x;
  if (bid >= nblk) {
    int gb = bid - nblk;
    if (gb < T1) {
      gemm_tile<true, true>(sm, x, W1, B2, N, gb);
    } else {
      int base = (gb - T1) * 512 + t;
      for (int i = base; i < 16384; i += P2 * 512) {
        int k = i >> 7, n = i & 127;
        W2t[n * 128 + k] = f2bf(W2[i]);
      }
    }
    return;
  }
  scatter_block(sm, src, dst, E, gcur, tmp, cap, B, bid);
}

__global__ __launch_bounds__(512) void cnt_gemm1b_k(const unsigned int* __restrict__ tmp,
                                                    const int* __restrict__ gcur,
                                                    int N, int E, int cap, int B,
                                                    float* __restrict__ dinv,
                                                    int* __restrict__ rs,
                                                    unsigned short* __restrict__ col,
                                                    const float* __restrict__ x,
                                                    const float* __restrict__ W1,
                                                    unsigned short* __restrict__ B2,
                                                    int T1) {
  __shared__ SMemX sm;
  if ((int)blockIdx.x >= B) {
    gemm_tile<true, true>(sm, x, W1, B2, N, T1 + (int)blockIdx.x - B);
    return;
  }
  cntfill_block(sm, tmp, gcur, N, cap, B, dinv, rs, col, blockIdx.x);
}

template <bool AF32, bool WF32>
__global__ __launch_bounds__(512) void gemm_bf_k(const void* __restrict__ Ap,
                                                 const void* __restrict__ Wp,
                                                 unsigned short* __restrict__ C, int N) {
  __shared__ SMemX sm;
  gemm_tile<AF32, WF32>(sm, Ap, Wp, C, N, blockIdx.x);
}

template <typename CT>
__global__ __launch_bounds__(256) void agg32_k(const unsigned short* __restrict__ h,
                                               const int* __restrict__ rs,
                                               const CT* __restrict__ col,
                                               const float* __restrict__ dinv,
                                               const float* __restrict__ bias,
                                               unsigned short* __restrict__ outp, int n) {
  int wid = (blockIdx.x * blockDim.x + threadIdx.x) >> 6;
  int lane = threadIdx.x & 63;
  if (wid >= n) return;
  const int g = lane >> 4;
  const int l = lane & 15;
  float di = dinv[wid];
  f32x2 acc2[4];
  {
    uint4 sv = ((const uint4*)(h + (size_t)wid * 128))[l];
    float ws = (g == 0) ? di : 0.f;
    f32x2 wv; wv.x = ws; wv.y = ws;
    acc2[0] = unpk(sv.x) * wv;
    acc2[1] = unpk(sv.y) * wv;
    acc2[2] = unpk(sv.z) * wv;
    acc2[3] = unpk(sv.w) * wv;
  }
  agg_body<CT>(acc2, h, col, dinv, rs[wid], rs[wid + 1], g, l);
  if (g == 0) {
    float4 bA = *(const float4*)(bias + l * 8);
    float4 bB = *(const float4*)(bias + l * 8 + 4);
    float r0 = fmaxf(acc2[0].x * di + bA.x, 0.f);
    float r1 = fmaxf(acc2[0].y * di + bA.y, 0.f);
    float r2 = fmaxf(acc2[1].x * di + bA.z, 0.f);
    float r3 = fmaxf(acc2[1].y * di + bA.w, 0.f);
    float r4 = fmaxf(acc2[2].x * di + bB.x, 0.f);
    float r5 = fmaxf(acc2[2].y * di + bB.y, 0.f);
    float r6 = fmaxf(acc2[3].x * di + bB.z, 0.f);
    float r7 = fmaxf(acc2[3].y * di + bB.w, 0.f);
    u32x4 v;
    v.x = (unsigned)f2bf(r0) | ((unsigned)f2bf(r1) << 16);
    v.y = (unsigned)f2bf(r2) | ((unsigned)f2bf(r3) << 16);
    v.z = (unsigned)f2bf(r4) | ((unsigned)f2bf(r5) << 16);
    v.w = (unsigned)f2bf(r6) | ((unsigned)f2bf(r7) << 16);
    __builtin_nontemporal_store(v, (u32x4*)outp + (size_t)wid * 16 + l);
  }
}

__global__ __launch_bounds__(256) void pool_sum_k(const unsigned short* __restrict__ h,
                                                  const int* __restrict__ bat, int n,
                                                  float* __restrict__ gsums) {
  __shared__ float red[16][136];
  const int g = blockIdx.x / SPLITS;
  const int sp = blockIdx.x % SPLITS;
  const int t = threadIdx.x;
  const int slot = t >> 4;
  const int seg = t & 15;
  int lo;
  { int l = 0, r = n; while (l < r) { int m = (l + r) >> 1; if (bat[m] < g) l = m + 1; else r = m; } lo = l; }
  int hi;
  { int l = lo, r = n; while (l < r) { int m = (l + r) >> 1; if (bat[m] < g + 1) l = m + 1; else r = m; } hi = l; }
  int L = hi - lo;
  int chunk = (L + SPLITS - 1) / SPLITS;
  int i0 = lo + sp * chunk;
  int i1 = i0 + chunk; if (i1 > hi) i1 = hi;
  if (i0 >= i1) return;
  float a0 = 0.f, a1 = 0.f, a2 = 0.f, a3 = 0.f, a4 = 0.f, a5 = 0.f, a6 = 0.f, a7 = 0.f;
  for (int i = i0 + slot; i < i1; i += 16) {
    uint4 v = ((const uint4*)(h + (size_t)i * 128))[seg];
    a0 += bf2f((unsigned short)v.x);  a1 += bf2f((unsigned short)(v.x >> 16));
    a2 += bf2f((unsigned short)v.y);  a3 += bf2f((unsigned short)(v.y >> 16));
    a4 += bf2f((unsigned short)v.z);  a5 += bf2f((unsigned short)(v.z >> 16));
    a6 += bf2f((unsigned short)v.w);  a7 += bf2f((unsigned short)(v.w >> 16));
  }
  red[slot][seg * 8 + 0] = a0; red[slot][seg * 8 + 1] = a1;
  red[slot][seg * 8 + 2] = a2; red[slot][seg * 8 + 3] = a3;
  red[slot][seg * 8 + 4] = a4; red[slot][seg * 8 + 5] = a5;
  red[slot][seg * 8 + 6] = a6; red[slot][seg * 8 + 7] = a7;
  __syncthreads();
  if (t < 128) {
    float s = 0.f;
    #pragma unroll
    for (int k = 0; k < 16; k++) s += red[k][t];
    unsafeAtomicAdd(&gsums[g * 128 + t], s);
  }
}

__global__ __launch_bounds__(256) void classify_k(const float* __restrict__ gsums,
                                                  const int* __restrict__ bat, int n,
                                                  const float* __restrict__ Wc1,
                                                  const float* __restrict__ bc1,
                                                  const float* __restrict__ Wc2,
                                                  const float* __restrict__ bc2,
                                                  float* __restrict__ out, int nc) {
  __shared__ float gs[128];
  __shared__ float zs[128];
  const int g = blockIdx.x;
  const int t = threadIdx.x;
  int lo;
  { int l = 0, r = n; while (l < r) { int m = (l + r) >> 1; if (bat[m] < g) l = m + 1; else r = m; } lo = l; }
  int hi;
  { int l = lo, r = n; while (l < r) { int m = (l + r) >> 1; if (bat[m] < g + 1) l = m + 1; else r = m; } hi = l; }
  if (t < 128) {
    float c = (float)(hi - lo); if (c < 1.f) c = 1.f;
    gs[t] = gsums[g * 128 + t] / c;
  }
  __syncthreads();
  if (t < 128) {
    float a = bc1[t];
    for (int k = 0; k < 128; k++) a += gs[k] * Wc1[k * 128 + t];
    zs[t] = fmaxf(a, 0.f);
  }
  __syncthreads();
  if (t < nc) {
    float o = bc2[t];
    for (int k = 0; k < 128; k++) o += zs[k] * Wc2[k * nc + t];
    out[g * nc + t] = o;
  }
}

__global__ __launch_bounds__(256) void poolclassify2_k(const unsigned short* __restrict__ h,
                                                       const int* __restrict__ bat, int n,
                                                       const float* __restrict__ Wc1,
                                                       const float* __restrict__ bc1,
                                                       const float* __restrict__ Wc2,
                                                       const float* __restrict__ bc2,
                                                       float* __restrict__ out, int nc) {
  __shared__ float red[16][136];
  __shared__ float gs[128];
  __shared__ float zs[128];
  const int g = blockIdx.x;
  const int t = threadIdx.x;
  const int slot = t >> 4;
  const int seg = t & 15;
  int lo;
  { int l = 0, r = n; while (l < r) { int m = (l + r) >> 1; if (bat[m] < g) l = m + 1; else r = m; } lo = l; }
  int hi;
  { int l = lo, r = n; while (l < r) { int m = (l + r) >> 1; if (bat[m] < g + 1) l = m + 1; else r = m; } hi = l; }
  float a0 = 0.f, a1 = 0.f, a2 = 0.f, a3 = 0.f, a4 = 0.f, a5 = 0.f, a6 = 0.f, a7 = 0.f;
  for (int i = lo + slot; i < hi; i += 16) {
    uint4 v = ((const uint4*)(h + (size_t)i * 128))[seg];
    a0 += bf2f((unsigned short)v.x);  a1 += bf2f((unsigned short)(v.x >> 16));
    a2 += bf2f((unsigned short)v.y);  a3 += bf2f((unsigned short)(v.y >> 16));
    a4 += bf2f((unsigned short)v.z);  a5 += bf2f((unsigned short)(v.z >> 16));
    a6 += bf2f((unsigned short)v.w);  a7 += bf2f((unsigned short)(v.w >> 16));
  }
  red[slot][seg * 8 + 0] = a0; red[slot][seg * 8 + 1] = a1;
  red[slot][seg * 8 + 2] = a2; red[slot][seg * 8 + 3] = a3;
  red[slot][seg * 8 + 4] = a4; red[slot][seg * 8 + 5] = a5;
  red[slot][seg * 8 + 6] = a6; red[slot][seg * 8 + 7] = a7;
  __syncthreads();
  if (t < 128) {
    float c = (float)(hi - lo); if (c < 1.f) c = 1.f;
    float s = 0.f;
    #pragma unroll
    for (int k = 0; k < 16; k++) s += red[k][t];
    gs[t] = s / c;
  }
  __syncthreads();
  if (t < 128) {
    float a = bc1[t];
    for (int k = 0; k < 128; k++) a += gs[k] * Wc1[k * 128 + t];
    zs[t] = fmaxf(a, 0.f);
  }
  __syncthreads();
  if (t < nc) {
    float o = bc2[t];
    for (int k = 0; k < 128; k++) o += zs[k] * Wc2[k * nc + t];
    out[g * nc + t] = o;
  }
}

__global__ void count_edges_k(const int* __restrict__ dst, int E, int* __restrict__ cnt) {
  int e = blockIdx.x * blockDim.x + threadIdx.x;
  if (e < E) atomicAdd(&cnt[dst[e]], 1);
}
__global__ void dinv_k(const int* __restrict__ cnt, float* __restrict__ dinv, int n) {
  int i = blockIdx.x * blockDim.x + threadIdx.x;
  if (i < n) dinv[i] = rsqrtf((float)cnt[i] + 1.0f);
}
__global__ void fill_csr_k(const int* __restrict__ src, const int* __restrict__ dst, int E,
                           int* __restrict__ cursor, int* __restrict__ col) {
  int e = blockIdx.x * blockDim.x + threadIdx.x;
  if (e < E) {
    int d = dst[e], s = src[e];
    int pos = atomicAdd(&cursor[d], 1);
    col[pos] = s;
  }
}
__global__ void scan1_k(const int* __restrict__ cnt, int* __restrict__ rs,
                        int* __restrict__ partials, int n) {
  __shared__ int s[1024];
  int t = threadIdx.x;
  int gid = blockIdx.x * 1024 + t;
  int v = (gid < n) ? cnt[gid] : 0;
  s[t] = v;
  __syncthreads();
  for (int off = 1; off < 1024; off <<= 1) {
    int u = (t >= off) ? s[t - off] : 0;
    __syncthreads();
    s[t] += u;
    __syncthreads();
  }
  if (gid < n) rs[gid] = s[t] - v;
  if (t == 1023) partials[blockIdx.x] = s[1023];
}
__global__ void scan2_k(int* __restrict__ partials, int nb) {
  if (threadIdx.x == 0 && blockIdx.x == 0) {
    int acc = 0;
    for (int i = 0; i < nb; i++) { int v = partials[i]; partials[i] = acc; acc += v; }
  }
}
__global__ void scan3_k(int* __restrict__ rs, int* __restrict__ cursor,
                        const int* __restrict__ partials, int n, int total) {
  int gid = blockIdx.x * blockDim.x + threadIdx.x;
  if (gid < n) {
    int v = rs[gid] + partials[gid >> 10];
    rs[gid] = v;
    cursor[gid] = v;
  }
  if (gid == 0) rs[n] = total;
}

template <typename CT>
__global__ __launch_bounds__(256) void agg32i_k(const unsigned short* __restrict__ h,
                                                const int* __restrict__ rs,
                                                const CT* __restrict__ col,
                                                const float* __restrict__ dinv,
                                                const float* __restrict__ bias,
                                                unsigned short* __restrict__ outp, int n) {
  // identical to agg32_k; separate symbol for int-col fallback instantiation clarity
  int wid = (blockIdx.x * blockDim.x + threadIdx.x) >> 6;
  int lane = threadIdx.x & 63;
  if (wid >= n) return;
  const int g = lane >> 4;
  const int l = lane & 15;
  float di = dinv[wid];
  f32x2 acc2[4];
  {
    uint4 sv = ((const uint4*)(h + (size_t)wid * 128))[l];
    float ws = (g == 0) ? di : 0.f;
    f32x2 wv; wv.x = ws; wv.y = ws;
    acc2[0] = unpk(sv.x) * wv;
    acc2[1] = unpk(sv.y) * wv;
    acc2[2] = unpk(sv.z) * wv;
    acc2[3] = unpk(sv.w) * wv;
  }
  agg_body<CT>(acc2, h, col, dinv, rs[wid], rs[wid + 1], g, l);
  if (g == 0) {
    float4 bA = *(const float4*)(bias + l * 8);
    float4 bB = *(const float4*)(bias + l * 8 + 4);
    float r0 = fmaxf(acc2[0].x * di + bA.x, 0.f);
    float r1 = fmaxf(acc2[0].y * di + bA.y, 0.f);
    float r2 = fmaxf(acc2[1].x * di + bA.z, 0.f);
    float r3 = fmaxf(acc2[1].y * di + bA.w, 0.f);
    float r4 = fmaxf(acc2[2].x * di + bB.x, 0.f);
    float r5 = fmaxf(acc2[2].y * di + bB.y, 0.f);
    float r6 = fmaxf(acc2[3].x * di + bB.z, 0.f);
    float r7 = fmaxf(acc2[3].y * di + bB.w, 0.f);
    u32x4 v;
    v.x = (unsigned)f2bf(r0) | ((unsigned)f2bf(r1) << 16);
    v.y = (unsigned)f2bf(r2) | ((unsigned)f2bf(r3) << 16);
    v.z = (unsigned)f2bf(r4) | ((unsigned)f2bf(r5) << 16);
    v.w = (unsigned)f2bf(r6) | ((unsigned)f2bf(r7) << 16);
    __builtin_nontemporal_store(v, (u32x4*)outp + (size_t)wid * 16 + l);
  }
}

extern "C" void kernel_launch(void* const* d_in, const int* in_sizes, int n_in,
                              void* d_out, int out_size, void* d_ws, size_t ws_size,
                              hipStream_t stream) {
  const float* x   = (const float*)d_in[0];
  const int*   ei  = (const int*)d_in[1];
  const int*   bat = (const int*)d_in[2];
  const float* W1  = (const float*)d_in[3];
  const float* b1  = (const float*)d_in[4];
  const float* W2  = (const float*)d_in[5];
  const float* b2  = (const float*)d_in[6];
  const float* Wc1 = (const float*)d_in[7];
  const float* bc1 = (const float*)d_in[8];
  const float* Wc2 = (const float*)d_in[9];
  const float* bc2 = (const float*)d_in[10];
  float* out = (float*)d_out;

  const int N  = in_sizes[0] / 128;
  const int E  = in_sizes[1] / 2;
  const int NC = in_sizes[10];
  const int G  = out_size / NC;
  const int* src = ei;
  const int* dst = ei + E;
  (void)n_in; (void)ws_size;

  size_t off = 0;
  auto walloc = [&](size_t bytes) -> void* {
    void* p = (char*)d_ws + off;
    off += (bytes + 255) & ~(size_t)255;
    return p;
  };
  unsigned short* B2 = (unsigned short*)walloc((size_t)N * 128 * 2);
  unsigned short* B3 = (unsigned short*)walloc((size_t)N * 128 * 2);
  unsigned short* W1t = (unsigned short*)walloc(128 * 128 * 2);
  unsigned short* W2t = (unsigned short*)walloc(128 * 128 * 2);
  float* dinv = (float*)walloc((size_t)N * 4);
  int*   rs   = (int*)  walloc((size_t)(N + 1) * 4);
  float* gsums = (float*)walloc((size_t)G * 128 * 4);
  int*   gcur  = (int*)walloc(256 * 4);

  const bool small = (N <= 65535);
  const int gblocks = (N + 127) / 128;
  const int aggGrid = (N + 3) / 4;

  if (small) {
    const int B    = (N + 255) >> 8;
    const int nblk = (E + CHUNK - 1) / CHUNK;
    const int cap  = (E + B - 1) / B + 2048;
    unsigned short* col = (unsigned short*)walloc((size_t)E * 2);
    unsigned int*   tmp = (unsigned int*)  walloc((size_t)B * cap * 4);

    // ---- size the cooperative grid once (host-side queries, capture-safe) ----
    static int s_coopBlocks = -2;
    if (s_coopBlocks == -2) {
      s_coopBlocks = -1;
      int dev = 0;
      if (hipGetDevice(&dev) == hipSuccess) {
        hipDeviceProp_t prop;
        if (hipGetDeviceProperties(&prop, dev) == hipSuccess) {
          int perCU = 0;
          if (hipOccupancyMaxActiveBlocksPerMultiprocessor(&perCU, (const void*)mega_k, 512, 0) == hipSuccess && perCU > 0)
            s_coopBlocks = perCU * prop.multiProcessorCount;
        }
      }
    }

    bool usedCoop = false;
    if (s_coopBlocks > B + 8) {
      // build arg list (lvalues must persist through launch call)
      const int* a_src = src; const int* a_dst = dst; int a_E = E;
      int* a_gcur = gcur; unsigned int* a_tmp = tmp; int a_cap = cap; int a_B = B;
      const float* a_x = x; const float* a_W1 = W1; const float* a_W2 = W2;
      const float* a_b1 = b1; const float* a_b2 = b2; const int* a_bat = bat;
      const float* a_Wc1 = Wc1; const float* a_bc1 = bc1;
      const float* a_Wc2 = Wc2; const float* a_bc2 = bc2;
      float* a_out = out; int a_NC = NC; int a_G = G;
      unsigned short* a_B2 = B2; unsigned short* a_B3 = B3;
      float* a_dinv = dinv; int* a_rs = rs; unsigned short* a_col = col;
      float* a_gsums = gsums; int a_N = N; int a_nblk = nblk; int a_gblocks = gblocks;
      void* kargs[] = {
        (void*)&a_src, (void*)&a_dst, (void*)&a_E,
        (void*)&a_gcur, (void*)&a_tmp, (void*)&a_cap, (void*)&a_B,
        (void*)&a_x, (void*)&a_W1, (void*)&a_W2,
        (void*)&a_b1, (void*)&a_b2, (void*)&a_bat,
        (void*)&a_Wc1, (void*)&a_bc1, (void*)&a_Wc2, (void*)&a_bc2,
        (void*)&a_out, (void*)&a_NC, (void*)&a_G,
        (void*)&a_B2, (void*)&a_B3,
        (void*)&a_dinv, (void*)&a_rs, (void*)&a_col,
        (void*)&a_gsums, (void*)&a_N, (void*)&a_nblk, (void*)&a_gblocks };
      if (hipLaunchCooperativeKernel((const void*)mega_k, dim3(s_coopBlocks), dim3(512),
                                     kargs, 0, stream) == hipSuccess) {
        usedCoop = true;
      }
    }

    if (!usedCoop) {
      // ---- round-9 fallback sequence ----
      const int T1 = (gblocks * 3) / 5;
      const int P2 = 8;
      (void)hipMemsetAsync(gsums, 0, (size_t)G * 128 * 4 + 1024, stream);
      scat_gemm1a_k<<<nblk + T1 + P2, 512, 0, stream>>>(src, dst, E, gcur, tmp, cap, B,
                                                        x, W1, B2, N, nblk, T1, W2, W2t, P2);
      cnt_gemm1b_k<<<B + (gblocks - T1), 512, 0, stream>>>(tmp, gcur, N, E, cap, B,
                                                           dinv, rs, col, x, W1, B2, T1);
      agg32_k<unsigned short><<<aggGrid, 256, 0, stream>>>(B2, rs, col, dinv, b1, B3, N);
      gemm_bf_k<false, false><<<gblocks, 512, 0, stream>>>(B3, W2t, B2, N);
      agg32_k<unsigned short><<<aggGrid, 256, 0, stream>>>(B2, rs, col, dinv, b2, B3, N);
      pool_sum_k<<<G * SPLITS, 256, 0, stream>>>(B3, bat, N, gsums);
      classify_k<<<G, 256, 0, stream>>>(gsums, bat, N, Wc1, bc1, Wc2, bc2, out, NC);
    }
  } else {
    const int nb = (N + 1023) / 1024;
    int* cnt    = (int*)walloc((size_t)N * 4);
    int* cursor = (int*)walloc((size_t)N * 4);
    int* coli   = (int*)walloc((size_t)E * 4);
    int* partials = (int*)walloc(256 * 4);
    prep_k<<<128, 256, 0, stream>>>(W1, W2, W1t, W2t, cnt /*dummy*/, 0, gsums, G * 128);
    (void)hipMemsetAsync(cnt, 0, (size_t)N * 4, stream);
    count_edges_k<<<(E + 255) / 256, 256, 0, stream>>>(dst, E, cnt);
    scan1_k<<<nb, 1024, 0, stream>>>(cnt, rs, partials, N);
    scan2_k<<<1, 64, 0, stream>>>(partials, nb);
    scan3_k<<<(N + 255) / 256, 256, 0, stream>>>(rs, cursor, partials, N, E);
    dinv_k<<<(N + 255) / 256, 256, 0, stream>>>(cnt, dinv, N);
    fill_csr_k<<<(E + 255) / 256, 256, 0, stream>>>(src, dst, E, cursor, coli);

    gemm_bf_k<true, false><<<gblocks, 512, 0, stream>>>(x, W1t, B2, N);
    agg32i_k<int><<<aggGrid, 256, 0, stream>>>(B2, rs, coli, dinv, b1, B3, N);
    gemm_bf_k<false, false><<<gblocks, 512, 0, stream>>>(B3, W2t, B2, N);
    agg32i_k<int><<<aggGrid, 256, 0, stream>>>(B2, rs, coli, dinv, b2, B3, N);
    poolclassify2_k<<<G, 256, 0, stream>>>(B3, bat, N, Wc1, bc1, Wc2, bc2, out, NC);
  }
}

// Round 11
// 258.192 us; speedup vs baseline: 2.2363x; 2.2363x over previous
//
#include <hip/hip_runtime.h>
#include <cstdint>
#include <cstddef>

#define CHUNK 8192

typedef __attribute__((ext_vector_type(8))) short short8;
typedef __attribute__((ext_vector_type(4))) float f32x4;
typedef __attribute__((ext_vector_type(2))) float f32x2;
typedef __attribute__((ext_vector_type(4))) unsigned int u32x4;

__device__ __forceinline__ float bf2f(unsigned short u) {
  return __uint_as_float(((unsigned)u) << 16);
}
__device__ __forceinline__ unsigned short f2bf(float f) {
  unsigned u = __float_as_uint(f);
  u += 0x7fffu + ((u >> 16) & 1u);   // RNE
  return (unsigned short)(u >> 16);
}
// unpack a dword holding 2 bf16 into an f32 pair (lo, hi)
__device__ __forceinline__ f32x2 unpk(unsigned u) {
  f32x2 r;
  r.x = __uint_as_float(u << 16);
  r.y = __uint_as_float(u & 0xffff0000u);
  return r;
}
// packed fp32 FMA: a += b * c (single VOP3P instruction)
__device__ __forceinline__ void pkfma(f32x2& a, f32x2 b, f32x2 c) {
  asm("v_pk_fma_f32 %0, %1, %2, %0" : "+v"(a) : "v"(b), "v"(c));
}

// shared-memory overlay: gemm staging vs scatter scratch vs cntfill scratch
union SMemX {
  unsigned short ws[128 * 136];                          // 34816 B (gemm)
  struct { unsigned sorted[CHUNK];
           int h[256]; int lps[256]; int base_s[256]; int cur[256]; } sc;  // 36864 B
  struct { int c[256]; int cur[256]; int sb[256];
           unsigned short colL[12288]; } cf;             // 27648 B
};

// ---------------- prep (FALLBACK path only): W transpose -> bf16 ----------------
__global__ void prep_k(const float* __restrict__ W1, const float* __restrict__ W2,
                       unsigned short* __restrict__ W1t, unsigned short* __restrict__ W2t,
                       int* __restrict__ gcur, int B,
                       float* __restrict__ gsums, int GN) {
  int idx = blockIdx.x * 256 + threadIdx.x;   // grid 128
  const float* W = (idx < 16384) ? W1 : W2;
  unsigned short* Wt = (idx < 16384) ? W1t : W2t;
  int i = idx & 16383;
  int k = i >> 7, n = i & 127;
  Wt[n * 128 + k] = f2bf(W[i]);
  if (blockIdx.x == 0 && threadIdx.x < B) gcur[threadIdx.x] = 0;
  if (idx < GN) gsums[idx] = 0.f;
}

// ---------------- gemm tile body: 128-row tiles, 512 threads ----------------
// WF32: stage W from f32 [k][n] layout with transpose+convert (removes W1t dependency).
template <bool AF32, bool WF32>
__device__ __forceinline__ void gemm_tile(SMemX& sm, const void* Ap,
                                          const void* Wp,
                                          unsigned short* C, int N, int tile) {
  if (WF32) {
    const float* Wf = (const float*)Wp;
    for (int idx = threadIdx.x; idx < 16384; idx += 512) {
      int k = idx >> 7, n = idx & 127;
      sm.ws[n * 136 + k] = f2bf(Wf[idx]);
    }
  } else {
    const unsigned short* Wt = (const unsigned short*)Wp;
    for (int idx = threadIdx.x; idx < 2048; idx += 512) {
      int n = idx >> 4, c = idx & 15;
      *(uint4*)&sm.ws[n * 136 + c * 8] = ((const uint4*)Wt)[idx];
    }
  }
  __syncthreads();
  const int w = threadIdx.x >> 6;        // 0..7
  const int lane = threadIdx.x & 63;
  const int quad = lane >> 4, l16 = lane & 15;
  const int r = tile * 128 + w * 16 + l16;
  f32x4 acc[8] = {};
  #pragma unroll
  for (int ks = 0; ks < 4; ks++) {
    short8 a = {};
    if (r < N) {
      if (AF32) {
        const float* ar = (const float*)Ap + (size_t)r * 128 + ks * 32 + quad * 8;
        float4 u0 = *(const float4*)ar;
        float4 u1 = *(const float4*)(ar + 4);
        a[0] = (short)f2bf(u0.x); a[1] = (short)f2bf(u0.y);
        a[2] = (short)f2bf(u0.z); a[3] = (short)f2bf(u0.w);
        a[4] = (short)f2bf(u1.x); a[5] = (short)f2bf(u1.y);
        a[6] = (short)f2bf(u1.z); a[7] = (short)f2bf(u1.w);
      } else {
        a = *(const short8*)((const unsigned short*)Ap + (size_t)r * 128 + ks * 32 + quad * 8);
      }
    }
    #pragma unroll
    for (int t = 0; t < 8; t++) {
      short8 bF = *(const short8*)&sm.ws[(t * 16 + l16) * 136 + ks * 32 + quad * 8];
      acc[t] = __builtin_amdgcn_mfma_f32_16x16x32_bf16(a, bF, acc[t], 0, 0, 0);
    }
  }
  __syncthreads();
  unsigned short* Cs = sm.ws;
  {
    int rloc = w * 16 + quad * 4;
    #pragma unroll
    for (int t = 0; t < 8; t++)
      #pragma unroll
      for (int rg = 0; rg < 4; rg++)
        Cs[(rloc + rg) * 132 + t * 16 + l16] = f2bf(acc[t][rg]);
  }
  __syncthreads();
  const int r0 = tile * 128;
  for (int idx = threadIdx.x; idx < 2048; idx += 512) {
    int row = idx >> 4, c = idx & 15;
    int rr = r0 + row;
    if (rr < N) {
      uint2 a = *(uint2*)&Cs[row * 132 + c * 8];
      uint2 b = *(uint2*)&Cs[row * 132 + c * 8 + 4];
      ((uint4*)C)[(size_t)rr * 16 + c] = make_uint4(a.x, a.y, b.x, b.y);
    }
  }
}

// ---------------- mega launch A: scatter [0,nblk) | gemm1 tiles [0,T1) | prep W2t ----
__global__ __launch_bounds__(512) void scat_gemm1a_k(const int* __restrict__ src,
                                                     const int* __restrict__ dst, int E,
                                                     int* __restrict__ gcur,
                                                     unsigned int* __restrict__ tmp,
                                                     int cap, int B,
                                                     const float* __restrict__ x,
                                                     const float* __restrict__ W1,
                                                     unsigned short* __restrict__ B2, int N,
                                                     int nblk, int T1,
                                                     const float* __restrict__ W2,
                                                     unsigned short* __restrict__ W2t,
                                                     int P2) {
  __shared__ SMemX sm;
  const int t = threadIdx.x;
  const int bid = blockIdx.x;
  if (bid >= nblk) {
    int gb = bid - nblk;
    if (gb < T1) {
      gemm_tile<true, true>(sm, x, W1, B2, N, gb);
    } else {
      // prep W2t: transpose+convert 16384 elems across P2 blocks
      int base = (gb - T1) * 512 + t;
      for (int i = base; i < 16384; i += P2 * 512) {
        int k = i >> 7, n = i & 127;
        W2t[n * 128 + k] = f2bf(W2[i]);
      }
    }
    return;
  }
  // ---- scatter role (identical logic to round-8 scatter_sort_k) ----
  if (t < 256) sm.sc.h[t] = 0;
  __syncthreads();
  int e0 = bid * CHUNK;
  int e1 = e0 + CHUNK; if (e1 > E) e1 = E;
  int m = e1 - e0;
  for (int i = t; i < m; i += 512) {
    atomicAdd(&sm.sc.h[dst[e0 + i] >> 8], 1);
  }
  __syncthreads();
  int v = (t < 256) ? sm.sc.h[t] : 0;
  if (t < 256) sm.sc.lps[t] = v;
  __syncthreads();
  for (int off = 1; off < 256; off <<= 1) {
    int u = (t >= off && t < 256) ? sm.sc.lps[t - off] : 0;
    __syncthreads();
    if (t < 256) sm.sc.lps[t] += u;
    __syncthreads();
  }
  int incl = (t < 256) ? sm.sc.lps[t] : 0;
  if (t < B && v > 0) sm.sc.base_s[t] = atomicAdd(&gcur[t], v);
  if (t < 256) {
    sm.sc.cur[t] = 0;
    sm.sc.lps[t] = incl - v;     // exclusive prefix
  }
  __syncthreads();
  for (int i = t; i < m; i += 512) {
    int d = dst[e0 + i], s = src[e0 + i];
    int b = d >> 8;
    int r = atomicAdd(&sm.sc.cur[b], 1);
    sm.sc.sorted[sm.sc.lps[b] + r] = ((unsigned)b << 24) | ((unsigned)s << 8) | (unsigned)(d & 255);
  }
  __syncthreads();
  for (int i = t; i < m; i += 512) {
    unsigned u = sm.sc.sorted[i];
    int b = u >> 24;
    int p = sm.sc.base_s[b] + (i - sm.sc.lps[b]);
    if (p < cap) tmp[(size_t)b * cap + p] = u;
  }
}

// ---------------- launch B: cntfill [0,B) | gemm1 tiles [T1, gblocks) ----------------
__global__ __launch_bounds__(512) void cnt_gemm1b_k(const unsigned int* __restrict__ tmp,
                                                    const int* __restrict__ gcur,
                                                    int N, int E, int cap, int B,
                                                    float* __restrict__ dinv,
                                                    int* __restrict__ rs,
                                                    unsigned short* __restrict__ col,
                                                    const float* __restrict__ x,
                                                    const float* __restrict__ W1,
                                                    unsigned short* __restrict__ B2,
                                                    int T1) {
  __shared__ SMemX sm;
  const int t = threadIdx.x;
  if ((int)blockIdx.x >= B) {
    gemm_tile<true, true>(sm, x, W1, B2, N, T1 + (int)blockIdx.x - B);
    return;
  }
  int b = blockIdx.x;
  int cb = 0;
  if (t < B) { cb = gcur[t]; if (cb > cap) cb = cap; }
  if (t < 256) sm.cf.sb[t] = cb;
  __syncthreads();
  for (int off = 1; off < 256; off <<= 1) {
    int u = (t >= off && t < 256) ? sm.cf.sb[t - off] : 0;
    __syncthreads();
    if (t < 256) sm.cf.sb[t] += u;
    __syncthreads();
  }
  int base_b = (b > 0) ? sm.cf.sb[b - 1] : 0;
  int cnt_b = sm.cf.sb[b] - base_b;
  if (b == 0 && t == 0) rs[N] = sm.cf.sb[B - 1];
  const unsigned* tb = tmp + (size_t)b * cap;
  if (t < 256) sm.cf.c[t] = 0;
  __syncthreads();
  for (int i = t; i < cnt_b; i += 512) atomicAdd(&sm.cf.c[tb[i] & 255u], 1);
  __syncthreads();
  int v = (t < 256) ? sm.cf.c[t] : 0;
  if (t < 256) sm.cf.cur[t] = v;
  __syncthreads();
  for (int off = 1; off < 256; off <<= 1) {
    int u = (t >= off && t < 256) ? sm.cf.cur[t - off] : 0;
    __syncthreads();
    if (t < 256) sm.cf.cur[t] += u;
    __syncthreads();
  }
  int rsv = (t < 256) ? (base_b + sm.cf.cur[t] - v) : 0;
  int node = (b << 8) + t;
  if (t < 256 && node < N) {
    rs[node] = rsv;
    dinv[node] = rsqrtf((float)v + 1.0f);
  }
  __syncthreads();
  if (cnt_b <= 12288) {
    if (t < 256) sm.cf.cur[t] = rsv - base_b;
    __syncthreads();
    for (int i = t; i < cnt_b; i += 512) {
      unsigned u = tb[i];
      int lpos = atomicAdd(&sm.cf.cur[u & 255u], 1);
      sm.cf.colL[lpos] = (unsigned short)((u >> 8) & 0xFFFFu);
    }
    __syncthreads();
    for (int i = t; i < cnt_b; i += 512) col[base_b + i] = sm.cf.colL[i];
  } else {
    if (t < 256) sm.cf.cur[t] = rsv;
    __syncthreads();
    for (int i = t; i < cnt_b; i += 512) {
      unsigned u = tb[i];
      int pos = atomicAdd(&sm.cf.cur[u & 255u], 1);
      col[pos] = (unsigned short)((u >> 8) & 0xFFFFu);
    }
  }
}

// standalone gemm (layer 2 + fallback), 512 threads
template <bool AF32, bool WF32>
__global__ __launch_bounds__(512) void gemm_bf_k(const void* __restrict__ Ap,
                                                 const void* __restrict__ Wp,
                                                 unsigned short* __restrict__ C, int N) {
  __shared__ SMemX sm;
  gemm_tile<AF32, WF32>(sm, Ap, Wp, C, N, blockIdx.x);
}

// ---------------- shared agg body: 32-edge unclamped fast path + 16-edge tail ----
template <typename CT>
__device__ __forceinline__ void agg_body(f32x2 (&acc2)[4],
                                         const unsigned short* __restrict__ h,
                                         const CT* __restrict__ col,
                                         const float* __restrict__ dinv,
                                         int beg, int end, int g, int l) {
  int base = beg;
  for (; base + 32 <= end; base += 32) {
    int s[8];
    float w[8];
    uint4 H[8];
    #pragma unroll
    for (int k = 0; k < 8; k++) s[k] = (int)col[base + 4 * k + g];
    #pragma unroll
    for (int k = 0; k < 8; k++) w[k] = dinv[s[k]];
    #pragma unroll
    for (int k = 0; k < 8; k++) H[k] = ((const uint4*)(h + (size_t)s[k] * 128))[l];
    #pragma unroll
    for (int k = 0; k < 8; k++) {
      f32x2 wv; wv.x = w[k]; wv.y = w[k];
      pkfma(acc2[0], unpk(H[k].x), wv);
      pkfma(acc2[1], unpk(H[k].y), wv);
      pkfma(acc2[2], unpk(H[k].z), wv);
      pkfma(acc2[3], unpk(H[k].w), wv);
    }
  }
  for (; base < end; base += 16) {
    int e0 = base + g, e1 = base + 4 + g, e2 = base + 8 + g, e3 = base + 12 + g;
    int i0 = (e0 < end) ? e0 : end - 1;
    int i1 = (e1 < end) ? e1 : end - 1;
    int i2 = (e2 < end) ? e2 : end - 1;
    int i3 = (e3 < end) ? e3 : end - 1;
    int s0 = (int)col[i0], s1 = (int)col[i1], s2 = (int)col[i2], s3 = (int)col[i3];
    float w0 = (e0 < end) ? dinv[s0] : 0.f;
    float w1 = (e1 < end) ? dinv[s1] : 0.f;
    float w2 = (e2 < end) ? dinv[s2] : 0.f;
    float w3 = (e3 < end) ? dinv[s3] : 0.f;
    uint4 h0 = ((const uint4*)(h + (size_t)s0 * 128))[l];
    uint4 h1 = ((const uint4*)(h + (size_t)s1 * 128))[l];
    uint4 h2 = ((const uint4*)(h + (size_t)s2 * 128))[l];
    uint4 h3 = ((const uint4*)(h + (size_t)s3 * 128))[l];
    f32x2 w0v; w0v.x = w0; w0v.y = w0;
    f32x2 w1v; w1v.x = w1; w1v.y = w1;
    f32x2 w2v; w2v.x = w2; w2v.y = w2;
    f32x2 w3v; w3v.x = w3; w3v.y = w3;
    pkfma(acc2[0], unpk(h0.x), w0v); pkfma(acc2[0], unpk(h1.x), w1v);
    pkfma(acc2[0], unpk(h2.x), w2v); pkfma(acc2[0], unpk(h3.x), w3v);
    pkfma(acc2[1], unpk(h0.y), w0v); pkfma(acc2[1], unpk(h1.y), w1v);
    pkfma(acc2[1], unpk(h2.y), w2v); pkfma(acc2[1], unpk(h3.y), w3v);
    pkfma(acc2[2], unpk(h0.z), w0v); pkfma(acc2[2], unpk(h1.z), w1v);
    pkfma(acc2[2], unpk(h2.z), w2v); pkfma(acc2[2], unpk(h3.z), w3v);
    pkfma(acc2[3], unpk(h0.w), w0v); pkfma(acc2[3], unpk(h1.w), w1v);
    pkfma(acc2[3], unpk(h2.w), w2v); pkfma(acc2[3], unpk(h3.w), w3v);
  }
  #pragma unroll
  for (int j = 0; j < 4; j++) {
    acc2[j].x += __shfl_xor(acc2[j].x, 16);
    acc2[j].y += __shfl_xor(acc2[j].y, 16);
    acc2[j].x += __shfl_xor(acc2[j].x, 32);
    acc2[j].y += __shfl_xor(acc2[j].y, 32);
  }
}

// ---------------- aggregation: writes bf16 rows (both layers) ----------------
template <typename CT>
__global__ __launch_bounds__(256) void agg32_k(const unsigned short* __restrict__ h,
                                               const int* __restrict__ rs,
                                               const CT* __restrict__ col,
                                               const float* __restrict__ dinv,
                                               const float* __restrict__ bias,
                                               unsigned short* __restrict__ outp, int n) {
  int wid = (blockIdx.x * blockDim.x + threadIdx.x) >> 6;
  int lane = threadIdx.x & 63;
  if (wid >= n) return;
  const int g = lane >> 4;
  const int l = lane & 15;
  float di = dinv[wid];
  f32x2 acc2[4];
  {
    uint4 sv = ((const uint4*)(h + (size_t)wid * 128))[l];
    float ws = (g == 0) ? di : 0.f;
    f32x2 wv; wv.x = ws; wv.y = ws;
    acc2[0] = unpk(sv.x) * wv;
    acc2[1] = unpk(sv.y) * wv;
    acc2[2] = unpk(sv.z) * wv;
    acc2[3] = unpk(sv.w) * wv;
  }
  agg_body<CT>(acc2, h, col, dinv, rs[wid], rs[wid + 1], g, l);
  if (g == 0) {
    float4 bA = *(const float4*)(bias + l * 8);
    float4 bB = *(const float4*)(bias + l * 8 + 4);
    float r0 = fmaxf(acc2[0].x * di + bA.x, 0.f);
    float r1 = fmaxf(acc2[0].y * di + bA.y, 0.f);
    float r2 = fmaxf(acc2[1].x * di + bA.z, 0.f);
    float r3 = fmaxf(acc2[1].y * di + bA.w, 0.f);
    float r4 = fmaxf(acc2[2].x * di + bB.x, 0.f);
    float r5 = fmaxf(acc2[2].y * di + bB.y, 0.f);
    float r6 = fmaxf(acc2[3].x * di + bB.z, 0.f);
    float r7 = fmaxf(acc2[3].y * di + bB.w, 0.f);
    u32x4 v;
    v.x = (unsigned)f2bf(r0) | ((unsigned)f2bf(r1) << 16);
    v.y = (unsigned)f2bf(r2) | ((unsigned)f2bf(r3) << 16);
    v.z = (unsigned)f2bf(r4) | ((unsigned)f2bf(r5) << 16);
    v.w = (unsigned)f2bf(r6) | ((unsigned)f2bf(r7) << 16);
    __builtin_nontemporal_store(v, (u32x4*)outp + (size_t)wid * 16 + l);
  }
}

// ---------------- parallel mean-pool partial sums ----------------
#define SPLITS 8
__global__ __launch_bounds__(256) void pool_sum_k(const unsigned short* __restrict__ h,
                                                  const int* __restrict__ bat, int n,
                                                  float* __restrict__ gsums) {
  __shared__ float red[16][136];
  const int g = blockIdx.x / SPLITS;
  const int sp = blockIdx.x % SPLITS;
  const int t = threadIdx.x;
  const int slot = t >> 4;
  const int seg = t & 15;
  int lo;
  {
    int l = 0, r = n;
    while (l < r) { int m = (l + r) >> 1; if (bat[m] < g) l = m + 1; else r = m; }
    lo = l;
  }
  int hi;
  {
    int l = lo, r = n;
    while (l < r) { int m = (l + r) >> 1; if (bat[m] < g + 1) l = m + 1; else r = m; }
    hi = l;
  }
  int L = hi - lo;
  int chunk = (L + SPLITS - 1) / SPLITS;
  int i0 = lo + sp * chunk;
  int i1 = i0 + chunk; if (i1 > hi) i1 = hi;
  if (i0 >= i1) return;
  float a0 = 0.f, a1 = 0.f, a2 = 0.f, a3 = 0.f, a4 = 0.f, a5 = 0.f, a6 = 0.f, a7 = 0.f;
  for (int i = i0 + slot; i < i1; i += 16) {
    uint4 v = ((const uint4*)(h + (size_t)i * 128))[seg];
    a0 += bf2f((unsigned short)v.x);  a1 += bf2f((unsigned short)(v.x >> 16));
    a2 += bf2f((unsigned short)v.y);  a3 += bf2f((unsigned short)(v.y >> 16));
    a4 += bf2f((unsigned short)v.z);  a5 += bf2f((unsigned short)(v.z >> 16));
    a6 += bf2f((unsigned short)v.w);  a7 += bf2f((unsigned short)(v.w >> 16));
  }
  red[slot][seg * 8 + 0] = a0; red[slot][seg * 8 + 1] = a1;
  red[slot][seg * 8 + 2] = a2; red[slot][seg * 8 + 3] = a3;
  red[slot][seg * 8 + 4] = a4; red[slot][seg * 8 + 5] = a5;
  red[slot][seg * 8 + 6] = a6; red[slot][seg * 8 + 7] = a7;
  __syncthreads();
  if (t < 128) {
    float s = 0.f;
    #pragma unroll
    for (int k = 0; k < 16; k++) s += red[k][t];
    unsafeAtomicAdd(&gsums[g * 128 + t], s);
  }
}

// ---------------- classifier on pooled sums (tiny; verified) ----------------
__global__ __launch_bounds__(256) void classify_k(const float* __restrict__ gsums,
                                                  const int* __restrict__ bat, int n,
                                                  const float* __restrict__ Wc1,
                                                  const float* __restrict__ bc1,
                                                  const float* __restrict__ Wc2,
                                                  const float* __restrict__ bc2,
                                                  float* __restrict__ out, int nc) {
  __shared__ float gs[128];
  __shared__ float zs[128];
  const int g = blockIdx.x;
  const int t = threadIdx.x;
  int lo;
  {
    int l = 0, r = n;
    while (l < r) { int m = (l + r) >> 1; if (bat[m] < g) l = m + 1; else r = m; }
    lo = l;
  }
  int hi;
  {
    int l = lo, r = n;
    while (l < r) { int m = (l + r) >> 1; if (bat[m] < g + 1) l = m + 1; else r = m; }
    hi = l;
  }
  if (t < 128) {
    float c = (float)(hi - lo); if (c < 1.f) c = 1.f;
    gs[t] = gsums[g * 128 + t] / c;
  }
  __syncthreads();
  if (t < 128) {
    float a = bc1[t];
    for (int k = 0; k < 128; k++) a += gs[k] * Wc1[k * 128 + t];
    zs[t] = fmaxf(a, 0.f);
  }
  __syncthreads();
  if (t < nc) {
    float o = bc2[t];
    for (int k = 0; k < 128; k++) o += zs[k] * Wc2[k * nc + t];
    out[g * nc + t] = o;
  }
}

// ---------------- fallback pool+classify (N > 65535 path) ----------------
__global__ __launch_bounds__(256) void poolclassify2_k(const unsigned short* __restrict__ h,
                                                       const int* __restrict__ bat, int n,
                                                       const float* __restrict__ Wc1,
                                                       const float* __restrict__ bc1,
                                                       const float* __restrict__ Wc2,
                                                       const float* __restrict__ bc2,
                                                       float* __restrict__ out, int nc) {
  __shared__ float red[16][136];
  __shared__ float gs[128];
  __shared__ float zs[128];
  const int g = blockIdx.x;
  const int t = threadIdx.x;
  const int slot = t >> 4;
  const int seg = t & 15;
  int lo;
  {
    int l = 0, r = n;
    while (l < r) { int m = (l + r) >> 1; if (bat[m] < g) l = m + 1; else r = m; }
    lo = l;
  }
  int hi;
  {
    int l = lo, r = n;
    while (l < r) { int m = (l + r) >> 1; if (bat[m] < g + 1) l = m + 1; else r = m; }
    hi = l;
  }
  float a0 = 0.f, a1 = 0.f, a2 = 0.f, a3 = 0.f, a4 = 0.f, a5 = 0.f, a6 = 0.f, a7 = 0.f;
  for (int i = lo + slot; i < hi; i += 16) {
    uint4 v = ((const uint4*)(h + (size_t)i * 128))[seg];
    a0 += bf2f((unsigned short)v.x);  a1 += bf2f((unsigned short)(v.x >> 16));
    a2 += bf2f((unsigned short)v.y);  a3 += bf2f((unsigned short)(v.y >> 16));
    a4 += bf2f((unsigned short)v.z);  a5 += bf2f((unsigned short)(v.z >> 16));
    a6 += bf2f((unsigned short)v.w);  a7 += bf2f((unsigned short)(v.w >> 16));
  }
  red[slot][seg * 8 + 0] = a0; red[slot][seg * 8 + 1] = a1;
  red[slot][seg * 8 + 2] = a2; red[slot][seg * 8 + 3] = a3;
  red[slot][seg * 8 + 4] = a4; red[slot][seg * 8 + 5] = a5;
  red[slot][seg * 8 + 6] = a6; red[slot][seg * 8 + 7] = a7;
  __syncthreads();
  if (t < 128) {
    float c = (float)(hi - lo); if (c < 1.f) c = 1.f;
    float s = 0.f;
    #pragma unroll
    for (int k = 0; k < 16; k++) s += red[k][t];
    gs[t] = s / c;
  }
  __syncthreads();
  if (t < 128) {
    float a = bc1[t];
    for (int k = 0; k < 128; k++) a += gs[k] * Wc1[k * 128 + t];
    zs[t] = fmaxf(a, 0.f);
  }
  __syncthreads();
  if (t < nc) {
    float o = bc2[t];
    for (int k = 0; k < 128; k++) o += zs[k] * Wc2[k * nc + t];
    out[g * nc + t] = o;
  }
}

// ---------------- fallback CSR build (N > 65535) ----------------
__global__ void count_edges_k(const int* __restrict__ dst, int E, int* __restrict__ cnt) {
  int e = blockIdx.x * blockDim.x + threadIdx.x;
  if (e < E) atomicAdd(&cnt[dst[e]], 1);
}
__global__ void dinv_k(const int* __restrict__ cnt, float* __restrict__ dinv, int n) {
  int i = blockIdx.x * blockDim.x + threadIdx.x;
  if (i < n) dinv[i] = rsqrtf((float)cnt[i] + 1.0f);
}
__global__ void fill_csr_k(const int* __restrict__ src, const int* __restrict__ dst, int E,
                           int* __restrict__ cursor, int* __restrict__ col) {
  int e = blockIdx.x * blockDim.x + threadIdx.x;
  if (e < E) {
    int d = dst[e], s = src[e];
    int pos = atomicAdd(&cursor[d], 1);
    col[pos] = s;
  }
}
__global__ void scan1_k(const int* __restrict__ cnt, int* __restrict__ rs,
                        int* __restrict__ partials, int n) {
  __shared__ int s[1024];
  int t = threadIdx.x;
  int gid = blockIdx.x * 1024 + t;
  int v = (gid < n) ? cnt[gid] : 0;
  s[t] = v;
  __syncthreads();
  for (int off = 1; off < 1024; off <<= 1) {
    int u = (t >= off) ? s[t - off] : 0;
    __syncthreads();
    s[t] += u;
    __syncthreads();
  }
  if (gid < n) rs[gid] = s[t] - v;
  if (t == 1023) partials[blockIdx.x] = s[1023];
}
__global__ void scan2_k(int* __restrict__ partials, int nb) {
  if (threadIdx.x == 0 && blockIdx.x == 0) {
    int acc = 0;
    for (int i = 0; i < nb; i++) { int v = partials[i]; partials[i] = acc; acc += v; }
  }
}
__global__ void scan3_k(int* __restrict__ rs, int* __restrict__ cursor,
                        const int* __restrict__ partials, int n, int total) {
  int gid = blockIdx.x * blockDim.x + threadIdx.x;
  if (gid < n) {
    int v = rs[gid] + partials[gid >> 10];
    rs[gid] = v;
    cursor[gid] = v;
  }
  if (gid == 0) rs[n] = total;
}

extern "C" void kernel_launch(void* const* d_in, const int* in_sizes, int n_in,
                              void* d_out, int out_size, void* d_ws, size_t ws_size,
                              hipStream_t stream) {
  const float* x   = (const float*)d_in[0];
  const int*   ei  = (const int*)d_in[1];
  const int*   bat = (const int*)d_in[2];
  const float* W1  = (const float*)d_in[3];
  const float* b1  = (const float*)d_in[4];
  const float* W2  = (const float*)d_in[5];
  const float* b2  = (const float*)d_in[6];
  const float* Wc1 = (const float*)d_in[7];
  const float* bc1 = (const float*)d_in[8];
  const float* Wc2 = (const float*)d_in[9];
  const float* bc2 = (const float*)d_in[10];
  float* out = (float*)d_out;

  const int N  = in_sizes[0] / 128;
  const int E  = in_sizes[1] / 2;
  const int NC = in_sizes[10];
  const int G  = out_size / NC;
  const int* src = ei;
  const int* dst = ei + E;
  (void)n_in; (void)ws_size;

  size_t off = 0;
  auto walloc = [&](size_t bytes) -> void* {
    void* p = (char*)d_ws + off;
    off += (bytes + 255) & ~(size_t)255;
    return p;
  };
  unsigned short* B2 = (unsigned short*)walloc((size_t)N * 128 * 2);
  unsigned short* B3 = (unsigned short*)walloc((size_t)N * 128 * 2);
  unsigned short* W1t = (unsigned short*)walloc(128 * 128 * 2);
  unsigned short* W2t = (unsigned short*)walloc(128 * 128 * 2);
  float* dinv = (float*)walloc((size_t)N * 4);
  int*   rs   = (int*)  walloc((size_t)(N + 1) * 4);
  // gsums (32 KB, 256-aligned) and gcur (1 KB) are contiguous -> ONE memset zeroes both
  float* gsums = (float*)walloc((size_t)G * 128 * 4);
  int*   gcur  = (int*)walloc(256 * 4);

  const bool small = (N <= 65535);
  const int gblocks = (N + 127) / 128;   // 128-row tiles @512 threads
  const int aggGrid = (N + 3) / 4;

  if (small) {
    const int B    = (N + 255) >> 8;
    const int nblk = (E + CHUNK - 1) / CHUNK;
    const int cap  = (E + B - 1) / B + 2048;
    const int T1   = (gblocks * 3) / 5;    // gemm1 tiles overlapped with scatter
    const int P2   = 8;                    // prep-W2t blocks
    unsigned short* col = (unsigned short*)walloc((size_t)E * 2);
    unsigned int*   tmp = (unsigned int*)  walloc((size_t)B * cap * 4);

    (void)hipMemsetAsync(gsums, 0, (size_t)G * 128 * 4 + 1024, stream);
    scat_gemm1a_k<<<nblk + T1 + P2, 512, 0, stream>>>(src, dst, E, gcur, tmp, cap, B,
                                                      x, W1, B2, N, nblk, T1, W2, W2t, P2);
    cnt_gemm1b_k<<<B + (gblocks - T1), 512, 0, stream>>>(tmp, gcur, N, E, cap, B,
                                                         dinv, rs, col, x, W1, B2, T1);
    agg32_k<unsigned short><<<aggGrid, 256, 0, stream>>>(B2, rs, col, dinv, b1, B3, N);
    gemm_bf_k<false, false><<<gblocks, 512, 0, stream>>>(B3, W2t, B2, N);
    agg32_k<unsigned short><<<aggGrid, 256, 0, stream>>>(B2, rs, col, dinv, b2, B3, N);
    pool_sum_k<<<G * SPLITS, 256, 0, stream>>>(B3, bat, N, gsums);
    classify_k<<<G, 256, 0, stream>>>(gsums, bat, N, Wc1, bc1, Wc2, bc2, out, NC);
  } else {
    const int nb = (N + 1023) / 1024;
    int* cnt    = (int*)walloc((size_t)N * 4);
    int* cursor = (int*)walloc((size_t)N * 4);
    int* col    = (int*)walloc((size_t)E * 4);
    int* partials = (int*)walloc(256 * 4);
    prep_k<<<128, 256, 0, stream>>>(W1, W2, W1t, W2t, cnt /*dummy*/, 0, gsums, G * 128);
    (void)hipMemsetAsync(cnt, 0, (size_t)N * 4, stream);
    count_edges_k<<<(E + 255) / 256, 256, 0, stream>>>(dst, E, cnt);
    scan1_k<<<nb, 1024, 0, stream>>>(cnt, rs, partials, N);
    scan2_k<<<1, 64, 0, stream>>>(partials, nb);
    scan3_k<<<(N + 255) / 256, 256, 0, stream>>>(rs, cursor, partials, N, E);
    dinv_k<<<(N + 255) / 256, 256, 0, stream>>>(cnt, dinv, N);
    fill_csr_k<<<(E + 255) / 256, 256, 0, stream>>>(src, dst, E, cursor, col);

    gemm_bf_k<true, false><<<gblocks, 512, 0, stream>>>(x, W1t, B2, N);
    agg32_k<int><<<aggGrid, 256, 0, stream>>>(B2, rs, col, dinv, b1, B3, N);
    gemm_bf_k<false, false><<<gblocks, 512, 0, stream>>>(B3, W2t, B2, N);
    agg32_k<int><<<aggGrid, 256, 0, stream>>>(B2, rs, col, dinv, b2, B3, N);
    poolclassify2_k<<<G, 256, 0, stream>>>(B3, bat, N, Wc1, bc1, Wc2, bc2, out, NC);
  }
}